// Round 8
// baseline (287.350 us; speedup 1.0000x reference)
//
#include <hip/hip_runtime.h>

#define HIDDEN 2048
#define NH 32
#define HD 16
#define PROJ 512
#define SEQ 2048

using f32x4    = __attribute__((ext_vector_type(4))) float;
using f32x2    = __attribute__((ext_vector_type(2))) float;
using bf16x8   = __attribute__((ext_vector_type(8))) __bf16;

__device__ __forceinline__ unsigned short f2bf(float x) {
  unsigned int u = __float_as_uint(x);
  u += 0x7FFFu + ((u >> 16) & 1u);   // RNE
  return (unsigned short)(u >> 16);
}

__device__ __forceinline__ f32x4 mfma_bf16(bf16x8 a, bf16x8 b, f32x4 c) {
  return __builtin_amdgcn_mfma_f32_16x16x32_bf16(a, b, c, 0, 0, 0);
}

// packed fp32 add (VOP3P)
__device__ __forceinline__ f32x2 pk_add(f32x2 a, f32x2 b) {
  f32x2 d;
  asm("v_pk_add_f32 %0, %1, %2" : "=v"(d) : "v"(a), "v"(b));
  return d;
}

// packed fp32->bf16 convert (RNE)
__device__ __forceinline__ unsigned int cvt_pk_bf16(float lo, float hi) {
  unsigned int d;
  asm("v_cvt_pk_bf16_f32 %0, %1, %2" : "=v"(d) : "v"(lo), "v"(hi));
  return d;
}

// pack 8 fp32 (two f32x4) -> bf16x8 via cvt_pk (RNE)
__device__ __forceinline__ bf16x8 pack8(f32x4 lo, f32x4 hi) {
  union { uint4 u; bf16x8 v; } r;
  r.u.x = cvt_pk_bf16(lo[0], lo[1]);
  r.u.y = cvt_pk_bf16(lo[2], lo[3]);
  r.u.z = cvt_pk_bf16(hi[0], hi[1]);
  r.u.w = cvt_pk_bf16(hi[2], hi[3]);
  return r.v;
}

#define GLDS16(gptr, lptr)                                              \
  __builtin_amdgcn_global_load_lds(                                     \
      (const __attribute__((address_space(1))) unsigned int*)(gptr),    \
      (__attribute__((address_space(3))) unsigned int*)(lptr), 16, 0, 0)

// ---------------------------------------------------------------------------
// QKV projection v14: 64x128 tile, BK=32, grid 768, fp32 staged DIRECTLY to
// LDS via global_load_lds (fire-and-forget, m97 drain structure); bf16
// conversion at fragment read (cvt_pk RNE -> identical bf16 values into the
// identical MFMA chain as the proven conv+bf16 version).
// fp32 swizzle: 8 groups of 4 floats/row; slot L holds global group
// (L&7)^(row&7); fragment read of group G uses slot G^(m&7).
// FIX vs R7: lane group qd reads fp32 groups {2qd, 2qd+1} (G0 = qd*2,
// NOT (qd&1)*2 — that bug read k=[0,16) twice for qd=2,3).
// z==2 (v) writes TRANSPOSED [B,NH,D,S].
// ---------------------------------------------------------------------------
__global__ __launch_bounds__(256)
void proj_kernel(const float* __restrict__ q, const float* __restrict__ k,
                 const float* __restrict__ v,
                 const float* __restrict__ Wq, const float* __restrict__ Wk,
                 const float* __restrict__ Wv,
                 unsigned short* __restrict__ qh, unsigned short* __restrict__ kh,
                 unsigned short* __restrict__ vt) {
  const int lin = blockIdx.x;
  const int e = lin & 7;          // XCD (dispatch % 8)
  const int t = lin >> 3;         // 0..95
  const int colt = t & 3;
  const int j = t >> 2;
  const int y = e + 8 * j;        // global row-strip 0..191
  const int z = y >> 6;
  const int row0 = (y & 63) * 64;
  const int col0 = colt * 128;

  const float* A = (z == 0) ? q : (z == 1) ? k : v;
  const float* Wb = (z == 0) ? Wq : (z == 1) ? Wk : Wv;
  const float scale = (z == 0) ? 0.18033688011112042f /* 0.125*log2(e) */ : 1.0f;

  __shared__ float Asf[64 * 32];    // 8 KB fp32
  __shared__ float Bsf[128 * 32];   // 16 KB fp32

  const int tid = threadIdx.x;
  const int w = tid >> 6;
  const int lane = tid & 63;
  const int ln = lane & 15;
  const int qd = lane >> 4;
  const int wm = w >> 1, wn = w & 1;

  // staging: pass p covers slots L=p*256+tid; row=L>>3, global group=(L&7)^(row&7)
  int aR[2], aG[2];
#pragma unroll
  for (int p = 0; p < 2; p++) {
    int L = p * 256 + tid;
    aR[p] = L >> 3;
    aG[p] = (L & 7) ^ (aR[p] & 7);
  }
  int bR[4], bG[4];
#pragma unroll
  for (int p = 0; p < 4; p++) {
    int L = p * 256 + tid;
    bR[p] = L >> 3;
    bG[p] = (L & 7) ^ (bR[p] & 7);
  }

  f32x4 acc[2][4];
#pragma unroll
  for (int mi = 0; mi < 2; mi++)
#pragma unroll
    for (int ni = 0; ni < 4; ni++) acc[mi][ni] = (f32x4){0.f, 0.f, 0.f, 0.f};

  const int G0 = qd * 2;          // lane reads k=[8qd, 8qd+8) = fp32 groups 2qd,2qd+1

  for (int k0 = 0; k0 < HIDDEN; k0 += 32) {
#pragma unroll
    for (int p = 0; p < 2; p++)
      GLDS16(A + (size_t)(row0 + aR[p]) * HIDDEN + k0 + aG[p] * 4,
             &Asf[(p * 256 + tid) * 4]);
#pragma unroll
    for (int p = 0; p < 4; p++)
      GLDS16(Wb + (size_t)(col0 + bR[p]) * HIDDEN + k0 + bG[p] * 4,
             &Bsf[(p * 256 + tid) * 4]);
    __syncthreads();

    bf16x8 af[2], bfv[4];
#pragma unroll
    for (int mi = 0; mi < 2; mi++) {
      int m = wm * 32 + mi * 16 + ln;
      f32x4 lo = *(const f32x4*)&Asf[(m * 8 + (G0 ^ (m & 7))) * 4];
      f32x4 hi = *(const f32x4*)&Asf[(m * 8 + ((G0 + 1) ^ (m & 7))) * 4];
      af[mi] = pack8(lo, hi);
    }
#pragma unroll
    for (int ni = 0; ni < 4; ni++) {
      int n = wn * 64 + ni * 16 + ln;
      f32x4 lo = *(const f32x4*)&Bsf[(n * 8 + (G0 ^ (n & 7))) * 4];
      f32x4 hi = *(const f32x4*)&Bsf[(n * 8 + ((G0 + 1) ^ (n & 7))) * 4];
      bfv[ni] = pack8(lo, hi);
    }
#pragma unroll
    for (int mi = 0; mi < 2; mi++)
#pragma unroll
      for (int ni = 0; ni < 4; ni++)
        acc[mi][ni] = mfma_bf16(af[mi], bfv[ni], acc[mi][ni]);
    __syncthreads();
  }

  if (z == 2) {
#pragma unroll
    for (int mi = 0; mi < 2; mi++)
#pragma unroll
      for (int ni = 0; ni < 4; ni++) {
        int h = (col0 + wn * 64 + ni * 16) >> 4;
        int grow0 = row0 + wm * 32 + mi * 16 + qd * 4;
        int b = grow0 >> 11, s0 = grow0 & 2047;
        uint2 o2;
        o2.x = f2bf(acc[mi][ni][0]) | ((unsigned)f2bf(acc[mi][ni][1]) << 16);
        o2.y = f2bf(acc[mi][ni][2]) | ((unsigned)f2bf(acc[mi][ni][3]) << 16);
        *(uint2*)&vt[((size_t)(b * NH + h) * HD + ln) * SEQ + s0] = o2;
      }
  } else {
    unsigned short* out = (z == 0) ? qh : kh;
#pragma unroll
    for (int mi = 0; mi < 2; mi++)
#pragma unroll
      for (int ni = 0; ni < 4; ni++) {
        int h = (col0 + wn * 64 + ni * 16) >> 4;
#pragma unroll
        for (int r = 0; r < 4; r++) {
          int grow = row0 + wm * 32 + mi * 16 + qd * 4 + r;
          int b = grow >> 11, s = grow & 2047;
          out[((size_t)(b * NH + h) * SEQ + s) * HD + ln] = f2bf(acc[mi][ni][r] * scale);
        }
      }
  }
}

// ---------------------------------------------------------------------------
// Flash attention v7 — EXACT R1 body (proven pass, ~56 us, absmax 9.77e-4).
// FROZEN: all restructures (R2/R3/R4) failed; only 2.5x bf16-ulp headroom.
// ---------------------------------------------------------------------------
__global__ __launch_bounds__(256, 4)
void flash_kernel(const unsigned short* __restrict__ qh,
                  const unsigned short* __restrict__ kh,
                  const unsigned short* __restrict__ vt,
                  unsigned short* __restrict__ attnb) {
  const int bh = blockIdx.x;
  const int b = bh >> 5, h = bh & 31;
  const int q0 = blockIdx.y * 128;
  const size_t hoff = (size_t)bh * SEQ * HD;
  const unsigned short* Qp = qh + hoff;
  const unsigned short* Kp = kh + hoff;
  const unsigned short* Vth = vt + hoff;    // [HD][SEQ] layout

  __shared__ unsigned short Qs[128 * 16];      // 4 KB
  __shared__ unsigned short Ks[2][128 * 16];   // 8 KB
  __shared__ unsigned short Vts[2][256 * 8];   // 8 KB, slot-swizzled [d][key]
  __shared__ unsigned short Ps[4][32 * 40];    // 10 KB, per-wave [q][key%32]
  __shared__ __align__(16) unsigned short Zz[8];

  const int tid = threadIdx.x;
  const int w = tid >> 6;
  const int lane = tid & 63;
  const int ln = lane & 15;
  const int qd = lane >> 4;
  const bool hiq = (qd >= 2);

  if (tid < 8) Zz[tid] = 0;

  // V staging slots: row d = tid>>4, stored group gi = (tid&15) ^ d
  const int vD = tid >> 4;
  const int vG = (tid & 15) ^ vD;

  // Q/K staging: row r = tid>>1, LDS slot s = tid&1 receives global half
  // h = s ^ ((r>>2)&1)  (pre-swizzled global source, linear LDS dest)
  const int qkOff = (tid >> 1) * 16 + (((tid & 1) ^ ((tid >> 3) & 1)) * 8);
  const int hsel = ((qd & 1) ^ ((ln >> 2) & 1)) * 8;

  GLDS16(Qp + (size_t)q0 * HD + qkOff, &Qs[tid * 8]);
  GLDS16(Kp + qkOff, &Ks[0][tid * 8]);
  GLDS16(Vth + (size_t)vD * SEQ + vG * 8, &Vts[0][tid * 8]);
  __syncthreads();

  // persistent Q B-fragments: B[n=q=w*32+ni*16+ln][k=d], d>=16 -> zeros
  bf16x8 aq[2];
#pragma unroll
  for (int ni = 0; ni < 2; ni++) {
    const unsigned short* src =
        hiq ? Zz : &Qs[(w * 32 + ni * 16 + ln) * 16 + hsel];
    aq[ni] = *(const bf16x8*)src;
  }

  f32x2 lsum2[2] = {{0.f, 0.f}, {0.f, 0.f}};
  f32x4 o_acc[2] = {{0.f, 0.f, 0.f, 0.f}, {0.f, 0.f, 0.f, 0.f}};
  unsigned short* Pw = &Ps[w][0];

  for (int t = 0; t < 16; t++) {
    const int buf = t & 1;
    if (t < 15) {
      GLDS16(Kp + (size_t)(t + 1) * 2048 + qkOff, &Ks[buf ^ 1][tid * 8]);
      GLDS16(Vth + (size_t)vD * SEQ + (t + 1) * 128 + vG * 8, &Vts[buf ^ 1][tid * 8]);
    }
    const unsigned short* Kb = &Ks[buf][0];
    const unsigned short* Vb = &Vts[buf][0];

#pragma unroll
    for (int c = 0; c < 4; c++) {
      f32x4 sc[2][2];
#pragma unroll
      for (int hf = 0; hf < 2; hf++) {
        int tile = c * 2 + hf;
        const unsigned short* asrc =
            hiq ? Zz : &Kb[(tile * 16 + ln) * 16 + hsel];
        bf16x8 ak = *(const bf16x8*)asrc;
#pragma unroll
        for (int ni = 0; ni < 2; ni++)
          sc[ni][hf] = mfma_bf16(ak, aq[ni], (f32x4){0.f, 0.f, 0.f, 0.f});
      }
      // av: row d=ln, chunk group (c*4+qd), swizzled slot = ln*16 + (g^ln)
      bf16x8 av = *(const bf16x8*)&Vb[(ln * 16 + ((c * 4 + qd) ^ ln)) * 8];

#pragma unroll
      for (int ni = 0; ni < 2; ni++) {
        float e0 = __builtin_amdgcn_exp2f(sc[ni][0][0]);
        float e1 = __builtin_amdgcn_exp2f(sc[ni][0][1]);
        float e2 = __builtin_amdgcn_exp2f(sc[ni][0][2]);
        float e3 = __builtin_amdgcn_exp2f(sc[ni][0][3]);
        float e4 = __builtin_amdgcn_exp2f(sc[ni][1][0]);
        float e5 = __builtin_amdgcn_exp2f(sc[ni][1][1]);
        float e6 = __builtin_amdgcn_exp2f(sc[ni][1][2]);
        float e7 = __builtin_amdgcn_exp2f(sc[ni][1][3]);
        f32x2 s01 = pk_add((f32x2){e0, e1}, (f32x2){e2, e3});
        f32x2 s23 = pk_add((f32x2){e4, e5}, (f32x2){e6, e7});
        lsum2[ni] = pk_add(lsum2[ni], pk_add(s01, s23));
        unsigned int d0 = cvt_pk_bf16(e0, e1);
        unsigned int d1 = cvt_pk_bf16(e2, e3);
        unsigned int d2 = cvt_pk_bf16(e4, e5);
        unsigned int d3 = cvt_pk_bf16(e6, e7);
        *(uint2*)&Pw[(ni * 16 + ln) * 40 + qd * 4] = make_uint2(d0, d1);
        *(uint2*)&Pw[(ni * 16 + ln) * 40 + 16 + qd * 4] = make_uint2(d2, d3);
      }

#pragma unroll
      for (int ni = 0; ni < 2; ni++) {
        bf16x8 bp = *(const bf16x8*)&Pw[(ni * 16 + ln) * 40 + qd * 8];
        o_acc[ni] = mfma_bf16(av, bp, o_acc[ni]);
      }
    }
    __syncthreads();
  }

  // epilogue: reduce l across the 4 qd-groups (2 shuffles), store bf16
#pragma unroll
  for (int ni = 0; ni < 2; ni++) {
    float l = lsum2[ni][0] + lsum2[ni][1];
    l += __shfl_xor(l, 16, 64);
    l += __shfl_xor(l, 32, 64);
    float invl = 1.0f / l;
    int s = q0 + w * 32 + ni * 16 + ln;
    f32x4 res = o_acc[ni] * invl;
    uint2 o2;
    o2.x = f2bf(res[0]) | ((unsigned)f2bf(res[1]) << 16);
    o2.y = f2bf(res[2]) | ((unsigned)f2bf(res[3]) << 16);
    *(uint2*)&attnb[((size_t)(b * SEQ + s)) * PROJ + h * HD + qd * 4] = o2;
  }
}

// ---------------------------------------------------------------------------
// Output projection v14: 128x128 tile, BK=32, grid 512. A (attnb bf16) via
// proven global_load_lds path; B (Wo) fp32 staged to LDS via global_load_lds
// with the 8-group swizzle, converted at fragment read (cvt_pk RNE).
// FIX vs R7: G0 = qd*2. Swapped MFMA operands -> transposed C fragment ->
// f32x4 coalesced stores.
// ---------------------------------------------------------------------------
__global__ __launch_bounds__(256)
void out_kernel(const unsigned short* __restrict__ attnb,
                const float* __restrict__ Wo,
                float* __restrict__ out) {
  const int lin = blockIdx.x;
  const int e = lin & 7;
  const int t = lin >> 3;                   // 0..63
  const int col0 = (e * 2 + (t & 1)) * 128;
  const int row0 = (t >> 1) * 128;

  __shared__ unsigned short As[128 * 32];   // 8 KB bf16
  __shared__ float Bsf[128 * 32];           // 16 KB fp32

  const int tid = threadIdx.x;
  const int w = tid >> 6;
  const int lane = tid & 63;
  const int ln = lane & 15;
  const int qd = lane >> 4;
  const int wm = w >> 1, wn = w & 1;

  const int aM = tid >> 2;
  const int aG = (tid & 3) ^ (aM & 3);
  int bR[4], bG[4];
#pragma unroll
  for (int p = 0; p < 4; p++) {
    int L = p * 256 + tid;
    bR[p] = L >> 3;
    bG[p] = (L & 7) ^ (bR[p] & 7);
  }

  f32x4 acc[2][2][4];
#pragma unroll
  for (int s2 = 0; s2 < 2; s2++)
#pragma unroll
    for (int mi = 0; mi < 2; mi++)
#pragma unroll
      for (int ni = 0; ni < 4; ni++) acc[s2][mi][ni] = (f32x4){0.f, 0.f, 0.f, 0.f};

  const int G0 = qd * 2;          // lane reads k=[8qd, 8qd+8) = fp32 groups 2qd,2qd+1

  for (int k0 = 0; k0 < PROJ; k0 += 32) {
    GLDS16(attnb + (size_t)(row0 + aM) * PROJ + k0 + aG * 8, &As[tid * 8]);
    GLDS16(attnb + (size_t)(row0 + 64 + aM) * PROJ + k0 + aG * 8, &As[(256 + tid) * 8]);
#pragma unroll
    for (int p = 0; p < 4; p++)
      GLDS16(Wo + (size_t)(col0 + bR[p]) * PROJ + k0 + bG[p] * 4,
             &Bsf[(p * 256 + tid) * 4]);
    __syncthreads();

    bf16x8 af[2][2], bfv[4];
#pragma unroll
    for (int s2 = 0; s2 < 2; s2++)
#pragma unroll
      for (int mi = 0; mi < 2; mi++) {
        int m = s2 * 64 + wm * 32 + mi * 16 + ln;
        af[s2][mi] = *(const bf16x8*)&As[(m * 4 + (qd ^ (m & 3))) * 8];
      }
#pragma unroll
    for (int ni = 0; ni < 4; ni++) {
      int n = wn * 64 + ni * 16 + ln;
      f32x4 lo = *(const f32x4*)&Bsf[(n * 8 + (G0 ^ (n & 7))) * 4];
      f32x4 hi = *(const f32x4*)&Bsf[(n * 8 + ((G0 + 1) ^ (n & 7))) * 4];
      bfv[ni] = pack8(lo, hi);
    }
    // swapped operands: C row dim = n (weight col), C col dim = m (s-row)
#pragma unroll
    for (int s2 = 0; s2 < 2; s2++)
#pragma unroll
      for (int mi = 0; mi < 2; mi++)
#pragma unroll
        for (int ni = 0; ni < 4; ni++)
          acc[s2][mi][ni] = mfma_bf16(bfv[ni], af[s2][mi], acc[s2][mi][ni]);
    __syncthreads();
  }

#pragma unroll
  for (int s2 = 0; s2 < 2; s2++)
#pragma unroll
    for (int mi = 0; mi < 2; mi++) {
      int grow = row0 + s2 * 64 + wm * 32 + mi * 16 + ln;
#pragma unroll
      for (int ni = 0; ni < 4; ni++) {
        int gcol = col0 + wn * 64 + ni * 16 + qd * 4;
        *(f32x4*)&out[(size_t)grow * HIDDEN + gcol] = acc[s2][mi][ni];
      }
    }
}

extern "C" void kernel_launch(void* const* d_in, const int* in_sizes, int n_in,
                              void* d_out, int out_size, void* d_ws, size_t ws_size,
                              hipStream_t stream) {
  const float* q  = (const float*)d_in[0];
  const float* k  = (const float*)d_in[1];
  const float* v  = (const float*)d_in[2];
  const float* Wq = (const float*)d_in[3];
  const float* Wk = (const float*)d_in[4];
  const float* Wv = (const float*)d_in[5];
  const float* Wo = (const float*)d_in[6];

  char* ws = (char*)d_ws;
  const size_t MB = 1024 * 1024;
  unsigned short* qh    = (unsigned short*)(ws);            // 4 MB
  unsigned short* kh    = (unsigned short*)(ws + 4 * MB);   // 4 MB
  unsigned short* vt    = (unsigned short*)(ws + 8 * MB);   // 4 MB [B,NH,D,S]
  unsigned short* attnb = (unsigned short*)(ws + 12 * MB);  // 4 MB

  proj_kernel<<<dim3(768), dim3(256), 0, stream>>>(q, k, v, Wq, Wk, Wv, qh, kh, vt);
  flash_kernel<<<dim3(64, 16), dim3(256), 0, stream>>>(qh, kh, vt, attnb);
  out_kernel<<<dim3(512), dim3(256), 0, stream>>>(attnb, Wo, (float*)d_out);

  (void)in_sizes; (void)n_in; (void)out_size; (void)ws_size;
}

// Round 9
// 266.571 us; speedup vs baseline: 1.0780x; 1.0780x over previous
//
#include <hip/hip_runtime.h>

#define HIDDEN 2048
#define NH 32
#define HD 16
#define PROJ 512
#define SEQ 2048

using f32x4    = __attribute__((ext_vector_type(4))) float;
using f32x2    = __attribute__((ext_vector_type(2))) float;
using bf16x8   = __attribute__((ext_vector_type(8))) __bf16;

__device__ __forceinline__ unsigned short f2bf(float x) {
  unsigned int u = __float_as_uint(x);
  u += 0x7FFFu + ((u >> 16) & 1u);   // RNE
  return (unsigned short)(u >> 16);
}

__device__ __forceinline__ f32x4 mfma_bf16(bf16x8 a, bf16x8 b, f32x4 c) {
  return __builtin_amdgcn_mfma_f32_16x16x32_bf16(a, b, c, 0, 0, 0);
}

// packed fp32 add (VOP3P)
__device__ __forceinline__ f32x2 pk_add(f32x2 a, f32x2 b) {
  f32x2 d;
  asm("v_pk_add_f32 %0, %1, %2" : "=v"(d) : "v"(a), "v"(b));
  return d;
}

// packed fp32->bf16 convert (RNE)
__device__ __forceinline__ unsigned int cvt_pk_bf16(float lo, float hi) {
  unsigned int d;
  asm("v_cvt_pk_bf16_f32 %0, %1, %2" : "=v"(d) : "v"(lo), "v"(hi));
  return d;
}

#define GLDS16(gptr, lptr)                                              \
  __builtin_amdgcn_global_load_lds(                                     \
      (const __attribute__((address_space(1))) unsigned int*)(gptr),    \
      (__attribute__((address_space(3))) unsigned int*)(lptr), 16, 0, 0)

// ---------------------------------------------------------------------------
// Fused pre-convert: q,k,v and Wq,Wk,Wv,Wo fp32 -> bf16 (RNE), one dispatch.
// (R5-proven verbatim. Fusion into proj/out tried twice — R6 reg-staged,
// R8 fp32-LDS — both lost: latency exposure / 2x LDS-pipe traffic.)
// ---------------------------------------------------------------------------
__global__ __launch_bounds__(256)
void conv_kernel(const float* __restrict__ q, const float* __restrict__ k,
                 const float* __restrict__ v,
                 const float* __restrict__ Wq, const float* __restrict__ Wk,
                 const float* __restrict__ Wv, const float* __restrict__ Wo,
                 unsigned short* __restrict__ qb, unsigned short* __restrict__ kb,
                 unsigned short* __restrict__ vb,
                 unsigned short* __restrict__ Wqb, unsigned short* __restrict__ Wkb,
                 unsigned short* __restrict__ Wvb, unsigned short* __restrict__ Wob) {
  const int bid = blockIdx.x;
  const float* src;
  unsigned short* dst;
  size_t i;
  if (bid < 24576) {
    const int z = bid >> 13;
    const int off = bid & 8191;
    src = (z == 0) ? q : (z == 1) ? k : v;
    dst = (z == 0) ? qb : (z == 1) ? kb : vb;
    i = ((size_t)off * 256 + threadIdx.x) * 4;
  } else {
    const int r = bid - 24576;
    const int z = r >> 10;
    const int off = r & 1023;
    src = (z == 0) ? Wq : (z == 1) ? Wk : (z == 2) ? Wv : Wo;
    dst = (z == 0) ? Wqb : (z == 1) ? Wkb : (z == 2) ? Wvb : Wob;
    i = ((size_t)off * 256 + threadIdx.x) * 4;
  }
  f32x4 x = *(const f32x4*)(src + i);
  uint2 p;
  p.x = f2bf(x[0]) | ((unsigned)f2bf(x[1]) << 16);
  p.y = f2bf(x[2]) | ((unsigned)f2bf(x[3]) << 16);
  *(uint2*)(dst + i) = p;
}

// ---------------------------------------------------------------------------
// QKV projection v15: 64x128 tile, BK=32, grid 768, bf16, DOUBLE-BUFFERED
// staging (flash-style: prefetch next k-tile BEFORE computing current, so
// load flight overlaps MFMA; the pre-barrier vmcnt drain finds loads done).
// Fragment formulas / MFMA order identical to proven R5 -> bit-identical.
// z==2 (v) writes TRANSPOSED [B,NH,D,S].
// ---------------------------------------------------------------------------
__global__ __launch_bounds__(256)
void proj_kernel(const unsigned short* __restrict__ qb,
                 const unsigned short* __restrict__ kb,
                 const unsigned short* __restrict__ vb,
                 const unsigned short* __restrict__ Wqb,
                 const unsigned short* __restrict__ Wkb,
                 const unsigned short* __restrict__ Wvb,
                 unsigned short* __restrict__ qh, unsigned short* __restrict__ kh,
                 unsigned short* __restrict__ vt) {
  const int lin = blockIdx.x;
  const int e = lin & 7;          // XCD (dispatch % 8)
  const int t = lin >> 3;         // 0..95
  const int colt = t & 3;
  const int j = t >> 2;
  const int y = e + 8 * j;        // global row-strip 0..191
  const int z = y >> 6;
  const int row0 = (y & 63) * 64;
  const int col0 = colt * 128;

  const unsigned short* A = (z == 0) ? qb : (z == 1) ? kb : vb;
  const unsigned short* Wb = (z == 0) ? Wqb : (z == 1) ? Wkb : Wvb;
  const float scale = (z == 0) ? 0.18033688011112042f /* 0.125*log2(e) */ : 1.0f;

  __shared__ unsigned short As[2][64 * 32];    // 2 x 4 KB
  __shared__ unsigned short Bs[2][128 * 32];   // 2 x 8 KB

  const int tid = threadIdx.x;
  const int w = tid >> 6;
  const int lane = tid & 63;
  const int ln = lane & 15;
  const int qd = lane >> 4;
  const int wm = w >> 1, wn = w & 1;

  const int aM = tid >> 2;
  const int aG = (tid & 3) ^ (aM & 3);
  int bN[2], bG[2];
#pragma unroll
  for (int s = 0; s < 2; s++) {
    int L = s * 256 + tid;
    bN[s] = L >> 2;
    bG[s] = (L & 3) ^ (bN[s] & 3);
  }

  const unsigned short* Aptr  = A + (size_t)(row0 + aM) * HIDDEN + aG * 8;
  const unsigned short* Bptr0 = Wb + (size_t)(col0 + bN[0]) * HIDDEN + bG[0] * 8;
  const unsigned short* Bptr1 = Wb + (size_t)(col0 + bN[1]) * HIDDEN + bG[1] * 8;

  f32x4 acc[2][4];
#pragma unroll
  for (int mi = 0; mi < 2; mi++)
#pragma unroll
    for (int ni = 0; ni < 4; ni++) acc[mi][ni] = (f32x4){0.f, 0.f, 0.f, 0.f};

  // prologue: stage k0 = 0 into buf 0
  GLDS16(Aptr, &As[0][tid * 8]);
  GLDS16(Bptr0, &Bs[0][tid * 8]);
  GLDS16(Bptr1, &Bs[0][(256 + tid) * 8]);
  __syncthreads();

  for (int k0 = 0; k0 < HIDDEN; k0 += 32) {
    const int cur = (k0 >> 5) & 1;
    // prefetch next k-tile (fire-and-forget; drains at the END barrier,
    // after its flight time has been covered by this step's compute)
    if (k0 + 32 < HIDDEN) {
      GLDS16(Aptr + k0 + 32, &As[cur ^ 1][tid * 8]);
      GLDS16(Bptr0 + k0 + 32, &Bs[cur ^ 1][tid * 8]);
      GLDS16(Bptr1 + k0 + 32, &Bs[cur ^ 1][(256 + tid) * 8]);
    }

    bf16x8 af[2], bfv[4];
#pragma unroll
    for (int mi = 0; mi < 2; mi++) {
      int m = wm * 32 + mi * 16 + ln;
      af[mi] = *(const bf16x8*)&As[cur][(m * 4 + (qd ^ (m & 3))) * 8];
    }
#pragma unroll
    for (int ni = 0; ni < 4; ni++) {
      int n = wn * 64 + ni * 16 + ln;
      bfv[ni] = *(const bf16x8*)&Bs[cur][(n * 4 + (qd ^ (n & 3))) * 8];
    }
#pragma unroll
    for (int mi = 0; mi < 2; mi++)
#pragma unroll
      for (int ni = 0; ni < 4; ni++)
        acc[mi][ni] = mfma_bf16(af[mi], bfv[ni], acc[mi][ni]);
    __syncthreads();
  }

  if (z == 2) {
#pragma unroll
    for (int mi = 0; mi < 2; mi++)
#pragma unroll
      for (int ni = 0; ni < 4; ni++) {
        int h = (col0 + wn * 64 + ni * 16) >> 4;
        int grow0 = row0 + wm * 32 + mi * 16 + qd * 4;
        int b = grow0 >> 11, s0 = grow0 & 2047;
        uint2 o2;
        o2.x = f2bf(acc[mi][ni][0]) | ((unsigned)f2bf(acc[mi][ni][1]) << 16);
        o2.y = f2bf(acc[mi][ni][2]) | ((unsigned)f2bf(acc[mi][ni][3]) << 16);
        *(uint2*)&vt[((size_t)(b * NH + h) * HD + ln) * SEQ + s0] = o2;
      }
  } else {
    unsigned short* out = (z == 0) ? qh : kh;
#pragma unroll
    for (int mi = 0; mi < 2; mi++)
#pragma unroll
      for (int ni = 0; ni < 4; ni++) {
        int h = (col0 + wn * 64 + ni * 16) >> 4;
#pragma unroll
        for (int r = 0; r < 4; r++) {
          int grow = row0 + wm * 32 + mi * 16 + qd * 4 + r;
          int b = grow >> 11, s = grow & 2047;
          out[((size_t)(b * NH + h) * SEQ + s) * HD + ln] = f2bf(acc[mi][ni][r] * scale);
        }
      }
  }
}

// ---------------------------------------------------------------------------
// Flash attention v7 — EXACT R1 body (proven pass, ~56 us, absmax 9.77e-4).
// FROZEN: all restructures (R2/R3/R4) failed; only 2.5x bf16-ulp headroom.
// ---------------------------------------------------------------------------
__global__ __launch_bounds__(256, 4)
void flash_kernel(const unsigned short* __restrict__ qh,
                  const unsigned short* __restrict__ kh,
                  const unsigned short* __restrict__ vt,
                  unsigned short* __restrict__ attnb) {
  const int bh = blockIdx.x;
  const int b = bh >> 5, h = bh & 31;
  const int q0 = blockIdx.y * 128;
  const size_t hoff = (size_t)bh * SEQ * HD;
  const unsigned short* Qp = qh + hoff;
  const unsigned short* Kp = kh + hoff;
  const unsigned short* Vth = vt + hoff;    // [HD][SEQ] layout

  __shared__ unsigned short Qs[128 * 16];      // 4 KB
  __shared__ unsigned short Ks[2][128 * 16];   // 8 KB
  __shared__ unsigned short Vts[2][256 * 8];   // 8 KB, slot-swizzled [d][key]
  __shared__ unsigned short Ps[4][32 * 40];    // 10 KB, per-wave [q][key%32]
  __shared__ __align__(16) unsigned short Zz[8];

  const int tid = threadIdx.x;
  const int w = tid >> 6;
  const int lane = tid & 63;
  const int ln = lane & 15;
  const int qd = lane >> 4;
  const bool hiq = (qd >= 2);

  if (tid < 8) Zz[tid] = 0;

  // V staging slots: row d = tid>>4, stored group gi = (tid&15) ^ d
  const int vD = tid >> 4;
  const int vG = (tid & 15) ^ vD;

  // Q/K staging: row r = tid>>1, LDS slot s = tid&1 receives global half
  // h = s ^ ((r>>2)&1)  (pre-swizzled global source, linear LDS dest)
  const int qkOff = (tid >> 1) * 16 + (((tid & 1) ^ ((tid >> 3) & 1)) * 8);
  const int hsel = ((qd & 1) ^ ((ln >> 2) & 1)) * 8;

  GLDS16(Qp + (size_t)q0 * HD + qkOff, &Qs[tid * 8]);
  GLDS16(Kp + qkOff, &Ks[0][tid * 8]);
  GLDS16(Vth + (size_t)vD * SEQ + vG * 8, &Vts[0][tid * 8]);
  __syncthreads();

  // persistent Q B-fragments: B[n=q=w*32+ni*16+ln][k=d], d>=16 -> zeros
  bf16x8 aq[2];
#pragma unroll
  for (int ni = 0; ni < 2; ni++) {
    const unsigned short* src =
        hiq ? Zz : &Qs[(w * 32 + ni * 16 + ln) * 16 + hsel];
    aq[ni] = *(const bf16x8*)src;
  }

  f32x2 lsum2[2] = {{0.f, 0.f}, {0.f, 0.f}};
  f32x4 o_acc[2] = {{0.f, 0.f, 0.f, 0.f}, {0.f, 0.f, 0.f, 0.f}};
  unsigned short* Pw = &Ps[w][0];

  for (int t = 0; t < 16; t++) {
    const int buf = t & 1;
    if (t < 15) {
      GLDS16(Kp + (size_t)(t + 1) * 2048 + qkOff, &Ks[buf ^ 1][tid * 8]);
      GLDS16(Vth + (size_t)vD * SEQ + (t + 1) * 128 + vG * 8, &Vts[buf ^ 1][tid * 8]);
    }
    const unsigned short* Kb = &Ks[buf][0];
    const unsigned short* Vb = &Vts[buf][0];

#pragma unroll
    for (int c = 0; c < 4; c++) {
      f32x4 sc[2][2];
#pragma unroll
      for (int hf = 0; hf < 2; hf++) {
        int tile = c * 2 + hf;
        const unsigned short* asrc =
            hiq ? Zz : &Kb[(tile * 16 + ln) * 16 + hsel];
        bf16x8 ak = *(const bf16x8*)asrc;
#pragma unroll
        for (int ni = 0; ni < 2; ni++)
          sc[ni][hf] = mfma_bf16(ak, aq[ni], (f32x4){0.f, 0.f, 0.f, 0.f});
      }
      // av: row d=ln, chunk group (c*4+qd), swizzled slot = ln*16 + (g^ln)
      bf16x8 av = *(const bf16x8*)&Vb[(ln * 16 + ((c * 4 + qd) ^ ln)) * 8];

#pragma unroll
      for (int ni = 0; ni < 2; ni++) {
        float e0 = __builtin_amdgcn_exp2f(sc[ni][0][0]);
        float e1 = __builtin_amdgcn_exp2f(sc[ni][0][1]);
        float e2 = __builtin_amdgcn_exp2f(sc[ni][0][2]);
        float e3 = __builtin_amdgcn_exp2f(sc[ni][0][3]);
        float e4 = __builtin_amdgcn_exp2f(sc[ni][1][0]);
        float e5 = __builtin_amdgcn_exp2f(sc[ni][1][1]);
        float e6 = __builtin_amdgcn_exp2f(sc[ni][1][2]);
        float e7 = __builtin_amdgcn_exp2f(sc[ni][1][3]);
        f32x2 s01 = pk_add((f32x2){e0, e1}, (f32x2){e2, e3});
        f32x2 s23 = pk_add((f32x2){e4, e5}, (f32x2){e6, e7});
        lsum2[ni] = pk_add(lsum2[ni], pk_add(s01, s23));
        unsigned int d0 = cvt_pk_bf16(e0, e1);
        unsigned int d1 = cvt_pk_bf16(e2, e3);
        unsigned int d2 = cvt_pk_bf16(e4, e5);
        unsigned int d3 = cvt_pk_bf16(e6, e7);
        *(uint2*)&Pw[(ni * 16 + ln) * 40 + qd * 4] = make_uint2(d0, d1);
        *(uint2*)&Pw[(ni * 16 + ln) * 40 + 16 + qd * 4] = make_uint2(d2, d3);
      }

#pragma unroll
      for (int ni = 0; ni < 2; ni++) {
        bf16x8 bp = *(const bf16x8*)&Pw[(ni * 16 + ln) * 40 + qd * 8];
        o_acc[ni] = mfma_bf16(av, bp, o_acc[ni]);
      }
    }
    __syncthreads();
  }

  // epilogue: reduce l across the 4 qd-groups (2 shuffles), store bf16
#pragma unroll
  for (int ni = 0; ni < 2; ni++) {
    float l = lsum2[ni][0] + lsum2[ni][1];
    l += __shfl_xor(l, 16, 64);
    l += __shfl_xor(l, 32, 64);
    float invl = 1.0f / l;
    int s = q0 + w * 32 + ni * 16 + ln;
    f32x4 res = o_acc[ni] * invl;
    uint2 o2;
    o2.x = f2bf(res[0]) | ((unsigned)f2bf(res[1]) << 16);
    o2.y = f2bf(res[2]) | ((unsigned)f2bf(res[3]) << 16);
    *(uint2*)&attnb[((size_t)(b * SEQ + s)) * PROJ + h * HD + qd * 4] = o2;
  }
}

// ---------------------------------------------------------------------------
// Output projection v15: 128x128 tile, BK=32, grid 512, bf16,
// DOUBLE-BUFFERED staging (same prefetch-then-compute order as proj v15).
// Swapped MFMA operands -> transposed C fragment -> f32x4 coalesced stores.
// Bit-identical accumulation chain to proven R5.
// ---------------------------------------------------------------------------
__global__ __launch_bounds__(256)
void out_kernel(const unsigned short* __restrict__ attnb,
                const unsigned short* __restrict__ Wob,
                float* __restrict__ out) {
  const int lin = blockIdx.x;
  const int e = lin & 7;
  const int t = lin >> 3;                   // 0..63
  const int col0 = (e * 2 + (t & 1)) * 128;
  const int row0 = (t >> 1) * 128;

  __shared__ unsigned short As[2][128 * 32];   // 2 x 8 KB
  __shared__ unsigned short Bs[2][128 * 32];   // 2 x 8 KB

  const int tid = threadIdx.x;
  const int w = tid >> 6;
  const int lane = tid & 63;
  const int ln = lane & 15;
  const int qd = lane >> 4;
  const int wm = w >> 1, wn = w & 1;

  const int aM = tid >> 2;
  const int aG = (tid & 3) ^ (aM & 3);
  int bN[2], bG[2];
#pragma unroll
  for (int s = 0; s < 2; s++) {
    int L = s * 256 + tid;
    bN[s] = L >> 2;
    bG[s] = (L & 3) ^ (bN[s] & 3);
  }

  const unsigned short* Aptr0 = attnb + (size_t)(row0 + aM) * PROJ + aG * 8;
  const unsigned short* Aptr1 = attnb + (size_t)(row0 + 64 + aM) * PROJ + aG * 8;
  const unsigned short* Bptr0 = Wob + (size_t)(col0 + bN[0]) * PROJ + bG[0] * 8;
  const unsigned short* Bptr1 = Wob + (size_t)(col0 + bN[1]) * PROJ + bG[1] * 8;

  f32x4 acc[2][2][4];
#pragma unroll
  for (int s2 = 0; s2 < 2; s2++)
#pragma unroll
    for (int mi = 0; mi < 2; mi++)
#pragma unroll
      for (int ni = 0; ni < 4; ni++) acc[s2][mi][ni] = (f32x4){0.f, 0.f, 0.f, 0.f};

  // prologue: stage k0 = 0 into buf 0
  GLDS16(Aptr0, &As[0][tid * 8]);
  GLDS16(Aptr1, &As[0][(256 + tid) * 8]);
  GLDS16(Bptr0, &Bs[0][tid * 8]);
  GLDS16(Bptr1, &Bs[0][(256 + tid) * 8]);
  __syncthreads();

  for (int k0 = 0; k0 < PROJ; k0 += 32) {
    const int cur = (k0 >> 5) & 1;
    if (k0 + 32 < PROJ) {
      GLDS16(Aptr0 + k0 + 32, &As[cur ^ 1][tid * 8]);
      GLDS16(Aptr1 + k0 + 32, &As[cur ^ 1][(256 + tid) * 8]);
      GLDS16(Bptr0 + k0 + 32, &Bs[cur ^ 1][tid * 8]);
      GLDS16(Bptr1 + k0 + 32, &Bs[cur ^ 1][(256 + tid) * 8]);
    }

    bf16x8 af[2][2], bfv[4];
#pragma unroll
    for (int s2 = 0; s2 < 2; s2++)
#pragma unroll
      for (int mi = 0; mi < 2; mi++) {
        int m = s2 * 64 + wm * 32 + mi * 16 + ln;
        af[s2][mi] = *(const bf16x8*)&As[cur][(m * 4 + (qd ^ (m & 3))) * 8];
      }
#pragma unroll
    for (int ni = 0; ni < 4; ni++) {
      int n = wn * 64 + ni * 16 + ln;
      bfv[ni] = *(const bf16x8*)&Bs[cur][(n * 4 + (qd ^ (n & 3))) * 8];
    }
    // swapped operands: C row dim = n (weight col), C col dim = m (s-row)
#pragma unroll
    for (int s2 = 0; s2 < 2; s2++)
#pragma unroll
      for (int mi = 0; mi < 2; mi++)
#pragma unroll
        for (int ni = 0; ni < 4; ni++)
          acc[s2][mi][ni] = mfma_bf16(bfv[ni], af[s2][mi], acc[s2][mi][ni]);
    __syncthreads();
  }

#pragma unroll
  for (int s2 = 0; s2 < 2; s2++)
#pragma unroll
    for (int mi = 0; mi < 2; mi++) {
      int grow = row0 + s2 * 64 + wm * 32 + mi * 16 + ln;
#pragma unroll
      for (int ni = 0; ni < 4; ni++) {
        int gcol = col0 + wn * 64 + ni * 16 + qd * 4;
        *(f32x4*)&out[(size_t)grow * HIDDEN + gcol] = acc[s2][mi][ni];
      }
    }
}

extern "C" void kernel_launch(void* const* d_in, const int* in_sizes, int n_in,
                              void* d_out, int out_size, void* d_ws, size_t ws_size,
                              hipStream_t stream) {
  const float* q  = (const float*)d_in[0];
  const float* k  = (const float*)d_in[1];
  const float* v  = (const float*)d_in[2];
  const float* Wq = (const float*)d_in[3];
  const float* Wk = (const float*)d_in[4];
  const float* Wv = (const float*)d_in[5];
  const float* Wo = (const float*)d_in[6];

  char* ws = (char*)d_ws;
  const size_t MB = 1024 * 1024;
  unsigned short* qh    = (unsigned short*)(ws);            // 4 MB
  unsigned short* kh    = (unsigned short*)(ws + 4 * MB);   // 4 MB
  unsigned short* vt    = (unsigned short*)(ws + 8 * MB);   // 4 MB [B,NH,D,S]
  unsigned short* attnb = (unsigned short*)(ws + 12 * MB);  // 4 MB
  unsigned short* Wqb   = (unsigned short*)(ws + 16 * MB);  // 2 MB
  unsigned short* Wkb   = (unsigned short*)(ws + 18 * MB);  // 2 MB
  unsigned short* Wvb   = (unsigned short*)(ws + 20 * MB);  // 2 MB
  unsigned short* Wob   = (unsigned short*)(ws + 22 * MB);  // 2 MB
  unsigned short* qb    = (unsigned short*)(ws + 24 * MB);  // 16 MB
  unsigned short* kb    = (unsigned short*)(ws + 40 * MB);  // 16 MB
  unsigned short* vb    = (unsigned short*)(ws + 56 * MB);  // 16 MB -> 72 MB

  conv_kernel<<<dim3(28672), dim3(256), 0, stream>>>(q, k, v, Wq, Wk, Wv, Wo,
                                                     qb, kb, vb, Wqb, Wkb, Wvb, Wob);
  proj_kernel<<<dim3(768), dim3(256), 0, stream>>>(qb, kb, vb, Wqb, Wkb, Wvb, qh, kh, vt);
  flash_kernel<<<dim3(64, 16), dim3(256), 0, stream>>>(qh, kh, vt, attnb);
  out_kernel<<<dim3(512), dim3(256), 0, stream>>>(attnb, Wob, (float*)d_out);

  (void)in_sizes; (void)n_in; (void)out_size; (void)ws_size;
}

// Round 10
// 255.265 us; speedup vs baseline: 1.1257x; 1.0443x over previous
//
#include <hip/hip_runtime.h>

#define HIDDEN 2048
#define NH 32
#define HD 16
#define PROJ 512
#define SEQ 2048

using f32x4    = __attribute__((ext_vector_type(4))) float;
using f32x2    = __attribute__((ext_vector_type(2))) float;
using bf16x8   = __attribute__((ext_vector_type(8))) __bf16;

__device__ __forceinline__ unsigned short f2bf(float x) {
  unsigned int u = __float_as_uint(x);
  u += 0x7FFFu + ((u >> 16) & 1u);   // RNE
  return (unsigned short)(u >> 16);
}

__device__ __forceinline__ f32x4 mfma_bf16(bf16x8 a, bf16x8 b, f32x4 c) {
  return __builtin_amdgcn_mfma_f32_16x16x32_bf16(a, b, c, 0, 0, 0);
}

// packed fp32 add (VOP3P)
__device__ __forceinline__ f32x2 pk_add(f32x2 a, f32x2 b) {
  f32x2 d;
  asm("v_pk_add_f32 %0, %1, %2" : "=v"(d) : "v"(a), "v"(b));
  return d;
}

// packed fp32->bf16 convert (RNE)
__device__ __forceinline__ unsigned int cvt_pk_bf16(float lo, float hi) {
  unsigned int d;
  asm("v_cvt_pk_bf16_f32 %0, %1, %2" : "=v"(d) : "v"(lo), "v"(hi));
  return d;
}

#define GLDS16(gptr, lptr)                                              \
  __builtin_amdgcn_global_load_lds(                                     \
      (const __attribute__((address_space(1))) unsigned int*)(gptr),    \
      (__attribute__((address_space(3))) unsigned int*)(lptr), 16, 0, 0)

// ---------------------------------------------------------------------------
// Fused pre-convert: q,k,v and Wq,Wk,Wv,Wo fp32 -> bf16 (RNE), one dispatch.
// (R5-proven verbatim; fusing into consumers lost twice, R6/R8.)
// ---------------------------------------------------------------------------
__global__ __launch_bounds__(256)
void conv_kernel(const float* __restrict__ q, const float* __restrict__ k,
                 const float* __restrict__ v,
                 const float* __restrict__ Wq, const float* __restrict__ Wk,
                 const float* __restrict__ Wv, const float* __restrict__ Wo,
                 unsigned short* __restrict__ qb, unsigned short* __restrict__ kb,
                 unsigned short* __restrict__ vb,
                 unsigned short* __restrict__ Wqb, unsigned short* __restrict__ Wkb,
                 unsigned short* __restrict__ Wvb, unsigned short* __restrict__ Wob) {
  const int bid = blockIdx.x;
  const float* src;
  unsigned short* dst;
  size_t i;
  if (bid < 24576) {
    const int z = bid >> 13;
    const int off = bid & 8191;
    src = (z == 0) ? q : (z == 1) ? k : v;
    dst = (z == 0) ? qb : (z == 1) ? kb : vb;
    i = ((size_t)off * 256 + threadIdx.x) * 4;
  } else {
    const int r = bid - 24576;
    const int z = r >> 10;
    const int off = r & 1023;
    src = (z == 0) ? Wq : (z == 1) ? Wk : (z == 2) ? Wv : Wo;
    dst = (z == 0) ? Wqb : (z == 1) ? Wkb : (z == 2) ? Wvb : Wob;
    i = ((size_t)off * 256 + threadIdx.x) * 4;
  }
  f32x4 x = *(const f32x4*)(src + i);
  uint2 p;
  p.x = f2bf(x[0]) | ((unsigned)f2bf(x[1]) << 16);
  p.y = f2bf(x[2]) | ((unsigned)f2bf(x[3]) << 16);
  *(uint2*)(dst + i) = p;
}

// ---------------------------------------------------------------------------
// QKV projection v16: 64x128 tile, BK=64 (was 32), grid 768 (3 blocks/CU),
// double-buffered. 32 K-steps instead of 64 -> half the barrier drains;
// 16 MFMA/wave/step. Rows are 8 groups of 16B; stage slot g = G^(row&7)
// (XOR algebra bit-exact-verified in R8); fragment G = kk*4+qd.
// Per-step kk=0 then kk=1, mi/ni order unchanged -> k-ascending accumulation
// = bit-identical to the BK=32 proven chain.
// z==2 (v) writes TRANSPOSED [B,NH,D,S].
// ---------------------------------------------------------------------------
__global__ __launch_bounds__(256)
void proj_kernel(const unsigned short* __restrict__ qb,
                 const unsigned short* __restrict__ kb,
                 const unsigned short* __restrict__ vb,
                 const unsigned short* __restrict__ Wqb,
                 const unsigned short* __restrict__ Wkb,
                 const unsigned short* __restrict__ Wvb,
                 unsigned short* __restrict__ qh, unsigned short* __restrict__ kh,
                 unsigned short* __restrict__ vt) {
  const int lin = blockIdx.x;
  const int e = lin & 7;          // XCD (dispatch % 8)
  const int t = lin >> 3;         // 0..95
  const int colt = t & 3;
  const int j = t >> 2;
  const int y = e + 8 * j;        // global row-strip 0..191
  const int z = y >> 6;
  const int row0 = (y & 63) * 64;
  const int col0 = colt * 128;

  const unsigned short* A = (z == 0) ? qb : (z == 1) ? kb : vb;
  const unsigned short* Wb = (z == 0) ? Wqb : (z == 1) ? Wkb : Wvb;
  const float scale = (z == 0) ? 0.18033688011112042f /* 0.125*log2(e) */ : 1.0f;

  __shared__ unsigned short As[2][64 * 64];    // 2 x 8 KB  (64 rows x 8 slots)
  __shared__ unsigned short Bs[2][128 * 64];   // 2 x 16 KB (128 rows x 8 slots)

  const int tid = threadIdx.x;
  const int w = tid >> 6;
  const int lane = tid & 63;
  const int ln = lane & 15;
  const int qd = lane >> 4;
  const int wm = w >> 1, wn = w & 1;

  // staging slots: pass p covers L = p*256+tid; row = L>>3; global 16B-group
  // = (L&7) ^ (row&7)
  int aR[2], aG[2];
#pragma unroll
  for (int p = 0; p < 2; p++) {
    int L = p * 256 + tid;
    aR[p] = L >> 3;
    aG[p] = (L & 7) ^ (aR[p] & 7);
  }
  int bR[4], bG[4];
#pragma unroll
  for (int p = 0; p < 4; p++) {
    int L = p * 256 + tid;
    bR[p] = L >> 3;
    bG[p] = (L & 7) ^ (bR[p] & 7);
  }

  f32x4 acc[2][4];
#pragma unroll
  for (int mi = 0; mi < 2; mi++)
#pragma unroll
    for (int ni = 0; ni < 4; ni++) acc[mi][ni] = (f32x4){0.f, 0.f, 0.f, 0.f};

  // prologue: stage k0 = 0 into buf 0
#pragma unroll
  for (int p = 0; p < 2; p++)
    GLDS16(A + (size_t)(row0 + aR[p]) * HIDDEN + aG[p] * 8, &As[0][(p * 256 + tid) * 8]);
#pragma unroll
  for (int p = 0; p < 4; p++)
    GLDS16(Wb + (size_t)(col0 + bR[p]) * HIDDEN + bG[p] * 8, &Bs[0][(p * 256 + tid) * 8]);
  __syncthreads();

  for (int k0 = 0; k0 < HIDDEN; k0 += 64) {
    const int cur = (k0 >> 6) & 1;
    if (k0 + 64 < HIDDEN) {
#pragma unroll
      for (int p = 0; p < 2; p++)
        GLDS16(A + (size_t)(row0 + aR[p]) * HIDDEN + k0 + 64 + aG[p] * 8,
               &As[cur ^ 1][(p * 256 + tid) * 8]);
#pragma unroll
      for (int p = 0; p < 4; p++)
        GLDS16(Wb + (size_t)(col0 + bR[p]) * HIDDEN + k0 + 64 + bG[p] * 8,
               &Bs[cur ^ 1][(p * 256 + tid) * 8]);
    }

#pragma unroll
    for (int kk = 0; kk < 2; kk++) {
      const int G = kk * 4 + qd;
      bf16x8 af[2], bfv[4];
#pragma unroll
      for (int mi = 0; mi < 2; mi++) {
        int m = wm * 32 + mi * 16 + ln;
        af[mi] = *(const bf16x8*)&As[cur][(m * 8 + (G ^ (m & 7))) * 8];
      }
#pragma unroll
      for (int ni = 0; ni < 4; ni++) {
        int n = wn * 64 + ni * 16 + ln;
        bfv[ni] = *(const bf16x8*)&Bs[cur][(n * 8 + (G ^ (n & 7))) * 8];
      }
#pragma unroll
      for (int mi = 0; mi < 2; mi++)
#pragma unroll
        for (int ni = 0; ni < 4; ni++)
          acc[mi][ni] = mfma_bf16(af[mi], bfv[ni], acc[mi][ni]);
    }
    __syncthreads();
  }

  if (z == 2) {
#pragma unroll
    for (int mi = 0; mi < 2; mi++)
#pragma unroll
      for (int ni = 0; ni < 4; ni++) {
        int h = (col0 + wn * 64 + ni * 16) >> 4;
        int grow0 = row0 + wm * 32 + mi * 16 + qd * 4;
        int b = grow0 >> 11, s0 = grow0 & 2047;
        uint2 o2;
        o2.x = f2bf(acc[mi][ni][0]) | ((unsigned)f2bf(acc[mi][ni][1]) << 16);
        o2.y = f2bf(acc[mi][ni][2]) | ((unsigned)f2bf(acc[mi][ni][3]) << 16);
        *(uint2*)&vt[((size_t)(b * NH + h) * HD + ln) * SEQ + s0] = o2;
      }
  } else {
    unsigned short* out = (z == 0) ? qh : kh;
#pragma unroll
    for (int mi = 0; mi < 2; mi++)
#pragma unroll
      for (int ni = 0; ni < 4; ni++) {
        int h = (col0 + wn * 64 + ni * 16) >> 4;
#pragma unroll
        for (int r = 0; r < 4; r++) {
          int grow = row0 + wm * 32 + mi * 16 + qd * 4 + r;
          int b = grow >> 11, s = grow & 2047;
          out[((size_t)(b * NH + h) * SEQ + s) * HD + ln] = f2bf(acc[mi][ni][r] * scale);
        }
      }
  }
}

// ---------------------------------------------------------------------------
// Flash attention v7 — EXACT R1 body (proven pass, ~55 us, absmax 9.77e-4).
// FROZEN: all restructures (R2/R3/R4) failed; only 2.5x bf16-ulp headroom.
// ---------------------------------------------------------------------------
__global__ __launch_bounds__(256, 4)
void flash_kernel(const unsigned short* __restrict__ qh,
                  const unsigned short* __restrict__ kh,
                  const unsigned short* __restrict__ vt,
                  unsigned short* __restrict__ attnb) {
  const int bh = blockIdx.x;
  const int b = bh >> 5, h = bh & 31;
  const int q0 = blockIdx.y * 128;
  const size_t hoff = (size_t)bh * SEQ * HD;
  const unsigned short* Qp = qh + hoff;
  const unsigned short* Kp = kh + hoff;
  const unsigned short* Vth = vt + hoff;    // [HD][SEQ] layout

  __shared__ unsigned short Qs[128 * 16];      // 4 KB
  __shared__ unsigned short Ks[2][128 * 16];   // 8 KB
  __shared__ unsigned short Vts[2][256 * 8];   // 8 KB, slot-swizzled [d][key]
  __shared__ unsigned short Ps[4][32 * 40];    // 10 KB, per-wave [q][key%32]
  __shared__ __align__(16) unsigned short Zz[8];

  const int tid = threadIdx.x;
  const int w = tid >> 6;
  const int lane = tid & 63;
  const int ln = lane & 15;
  const int qd = lane >> 4;
  const bool hiq = (qd >= 2);

  if (tid < 8) Zz[tid] = 0;

  // V staging slots: row d = tid>>4, stored group gi = (tid&15) ^ d
  const int vD = tid >> 4;
  const int vG = (tid & 15) ^ vD;

  // Q/K staging: row r = tid>>1, LDS slot s = tid&1 receives global half
  // h = s ^ ((r>>2)&1)  (pre-swizzled global source, linear LDS dest)
  const int qkOff = (tid >> 1) * 16 + (((tid & 1) ^ ((tid >> 3) & 1)) * 8);
  const int hsel = ((qd & 1) ^ ((ln >> 2) & 1)) * 8;

  GLDS16(Qp + (size_t)q0 * HD + qkOff, &Qs[tid * 8]);
  GLDS16(Kp + qkOff, &Ks[0][tid * 8]);
  GLDS16(Vth + (size_t)vD * SEQ + vG * 8, &Vts[0][tid * 8]);
  __syncthreads();

  // persistent Q B-fragments: B[n=q=w*32+ni*16+ln][k=d], d>=16 -> zeros
  bf16x8 aq[2];
#pragma unroll
  for (int ni = 0; ni < 2; ni++) {
    const unsigned short* src =
        hiq ? Zz : &Qs[(w * 32 + ni * 16 + ln) * 16 + hsel];
    aq[ni] = *(const bf16x8*)src;
  }

  f32x2 lsum2[2] = {{0.f, 0.f}, {0.f, 0.f}};
  f32x4 o_acc[2] = {{0.f, 0.f, 0.f, 0.f}, {0.f, 0.f, 0.f, 0.f}};
  unsigned short* Pw = &Ps[w][0];

  for (int t = 0; t < 16; t++) {
    const int buf = t & 1;
    if (t < 15) {
      GLDS16(Kp + (size_t)(t + 1) * 2048 + qkOff, &Ks[buf ^ 1][tid * 8]);
      GLDS16(Vth + (size_t)vD * SEQ + (t + 1) * 128 + vG * 8, &Vts[buf ^ 1][tid * 8]);
    }
    const unsigned short* Kb = &Ks[buf][0];
    const unsigned short* Vb = &Vts[buf][0];

#pragma unroll
    for (int c = 0; c < 4; c++) {
      f32x4 sc[2][2];
#pragma unroll
      for (int hf = 0; hf < 2; hf++) {
        int tile = c * 2 + hf;
        const unsigned short* asrc =
            hiq ? Zz : &Kb[(tile * 16 + ln) * 16 + hsel];
        bf16x8 ak = *(const bf16x8*)asrc;
#pragma unroll
        for (int ni = 0; ni < 2; ni++)
          sc[ni][hf] = mfma_bf16(ak, aq[ni], (f32x4){0.f, 0.f, 0.f, 0.f});
      }
      // av: row d=ln, chunk group (c*4+qd), swizzled slot = ln*16 + (g^ln)
      bf16x8 av = *(const bf16x8*)&Vb[(ln * 16 + ((c * 4 + qd) ^ ln)) * 8];

#pragma unroll
      for (int ni = 0; ni < 2; ni++) {
        float e0 = __builtin_amdgcn_exp2f(sc[ni][0][0]);
        float e1 = __builtin_amdgcn_exp2f(sc[ni][0][1]);
        float e2 = __builtin_amdgcn_exp2f(sc[ni][0][2]);
        float e3 = __builtin_amdgcn_exp2f(sc[ni][0][3]);
        float e4 = __builtin_amdgcn_exp2f(sc[ni][1][0]);
        float e5 = __builtin_amdgcn_exp2f(sc[ni][1][1]);
        float e6 = __builtin_amdgcn_exp2f(sc[ni][1][2]);
        float e7 = __builtin_amdgcn_exp2f(sc[ni][1][3]);
        f32x2 s01 = pk_add((f32x2){e0, e1}, (f32x2){e2, e3});
        f32x2 s23 = pk_add((f32x2){e4, e5}, (f32x2){e6, e7});
        lsum2[ni] = pk_add(lsum2[ni], pk_add(s01, s23));
        unsigned int d0 = cvt_pk_bf16(e0, e1);
        unsigned int d1 = cvt_pk_bf16(e2, e3);
        unsigned int d2 = cvt_pk_bf16(e4, e5);
        unsigned int d3 = cvt_pk_bf16(e6, e7);
        *(uint2*)&Pw[(ni * 16 + ln) * 40 + qd * 4] = make_uint2(d0, d1);
        *(uint2*)&Pw[(ni * 16 + ln) * 40 + 16 + qd * 4] = make_uint2(d2, d3);
      }

#pragma unroll
      for (int ni = 0; ni < 2; ni++) {
        bf16x8 bp = *(const bf16x8*)&Pw[(ni * 16 + ln) * 40 + qd * 8];
        o_acc[ni] = mfma_bf16(av, bp, o_acc[ni]);
      }
    }
    __syncthreads();
  }

  // epilogue: reduce l across the 4 qd-groups (2 shuffles), store bf16
#pragma unroll
  for (int ni = 0; ni < 2; ni++) {
    float l = lsum2[ni][0] + lsum2[ni][1];
    l += __shfl_xor(l, 16, 64);
    l += __shfl_xor(l, 32, 64);
    float invl = 1.0f / l;
    int s = q0 + w * 32 + ni * 16 + ln;
    f32x4 res = o_acc[ni] * invl;
    uint2 o2;
    o2.x = f2bf(res[0]) | ((unsigned)f2bf(res[1]) << 16);
    o2.y = f2bf(res[2]) | ((unsigned)f2bf(res[3]) << 16);
    *(uint2*)&attnb[((size_t)(b * SEQ + s)) * PROJ + h * HD + qd * 4] = o2;
  }
}

// ---------------------------------------------------------------------------
// Output projection v16: 128x128 tile, BK=64 (was 32), grid 512 (2/CU),
// double-buffered (64 KB LDS). 8 K-steps instead of 16. Same 8-group XOR
// staging; fragment G = kk*4+qd; kk-ascending accumulation = bit-identical.
// Swapped MFMA operands -> transposed C fragment -> f32x4 coalesced stores.
// ---------------------------------------------------------------------------
__global__ __launch_bounds__(256)
void out_kernel(const unsigned short* __restrict__ attnb,
                const unsigned short* __restrict__ Wob,
                float* __restrict__ out) {
  const int lin = blockIdx.x;
  const int e = lin & 7;
  const int t = lin >> 3;                   // 0..63
  const int col0 = (e * 2 + (t & 1)) * 128;
  const int row0 = (t >> 1) * 128;

  __shared__ unsigned short As[2][128 * 64];   // 2 x 16 KB
  __shared__ unsigned short Bs[2][128 * 64];   // 2 x 16 KB

  const int tid = threadIdx.x;
  const int w = tid >> 6;
  const int lane = tid & 63;
  const int ln = lane & 15;
  const int qd = lane >> 4;
  const int wm = w >> 1, wn = w & 1;

  int aR[4], aG[4], bR[4], bG[4];
#pragma unroll
  for (int p = 0; p < 4; p++) {
    int L = p * 256 + tid;
    aR[p] = L >> 3;
    aG[p] = (L & 7) ^ (aR[p] & 7);
    bR[p] = aR[p];
    bG[p] = aG[p];
  }

  f32x4 acc[2][2][4];
#pragma unroll
  for (int s2 = 0; s2 < 2; s2++)
#pragma unroll
    for (int mi = 0; mi < 2; mi++)
#pragma unroll
      for (int ni = 0; ni < 4; ni++) acc[s2][mi][ni] = (f32x4){0.f, 0.f, 0.f, 0.f};

  // prologue: stage k0 = 0 into buf 0
#pragma unroll
  for (int p = 0; p < 4; p++) {
    GLDS16(attnb + (size_t)(row0 + aR[p]) * PROJ + aG[p] * 8, &As[0][(p * 256 + tid) * 8]);
    GLDS16(Wob + (size_t)(col0 + bR[p]) * PROJ + bG[p] * 8, &Bs[0][(p * 256 + tid) * 8]);
  }
  __syncthreads();

  for (int k0 = 0; k0 < PROJ; k0 += 64) {
    const int cur = (k0 >> 6) & 1;
    if (k0 + 64 < PROJ) {
#pragma unroll
      for (int p = 0; p < 4; p++) {
        GLDS16(attnb + (size_t)(row0 + aR[p]) * PROJ + k0 + 64 + aG[p] * 8,
               &As[cur ^ 1][(p * 256 + tid) * 8]);
        GLDS16(Wob + (size_t)(col0 + bR[p]) * PROJ + k0 + 64 + bG[p] * 8,
               &Bs[cur ^ 1][(p * 256 + tid) * 8]);
      }
    }

#pragma unroll
    for (int kk = 0; kk < 2; kk++) {
      const int G = kk * 4 + qd;
      bf16x8 af[2][2], bfv[4];
#pragma unroll
      for (int s2 = 0; s2 < 2; s2++)
#pragma unroll
        for (int mi = 0; mi < 2; mi++) {
          int m = s2 * 64 + wm * 32 + mi * 16 + ln;
          af[s2][mi] = *(const bf16x8*)&As[cur][(m * 8 + (G ^ (m & 7))) * 8];
        }
#pragma unroll
      for (int ni = 0; ni < 4; ni++) {
        int n = wn * 64 + ni * 16 + ln;
        bfv[ni] = *(const bf16x8*)&Bs[cur][(n * 8 + (G ^ (n & 7))) * 8];
      }
      // swapped operands: C row dim = n (weight col), C col dim = m (s-row)
#pragma unroll
      for (int s2 = 0; s2 < 2; s2++)
#pragma unroll
        for (int mi = 0; mi < 2; mi++)
#pragma unroll
          for (int ni = 0; ni < 4; ni++)
            acc[s2][mi][ni] = mfma_bf16(bfv[ni], af[s2][mi], acc[s2][mi][ni]);
    }
    __syncthreads();
  }

#pragma unroll
  for (int s2 = 0; s2 < 2; s2++)
#pragma unroll
    for (int mi = 0; mi < 2; mi++) {
      int grow = row0 + s2 * 64 + wm * 32 + mi * 16 + ln;
#pragma unroll
      for (int ni = 0; ni < 4; ni++) {
        int gcol = col0 + wn * 64 + ni * 16 + qd * 4;
        *(f32x4*)&out[(size_t)grow * HIDDEN + gcol] = acc[s2][mi][ni];
      }
    }
}

extern "C" void kernel_launch(void* const* d_in, const int* in_sizes, int n_in,
                              void* d_out, int out_size, void* d_ws, size_t ws_size,
                              hipStream_t stream) {
  const float* q  = (const float*)d_in[0];
  const float* k  = (const float*)d_in[1];
  const float* v  = (const float*)d_in[2];
  const float* Wq = (const float*)d_in[3];
  const float* Wk = (const float*)d_in[4];
  const float* Wv = (const float*)d_in[5];
  const float* Wo = (const float*)d_in[6];

  char* ws = (char*)d_ws;
  const size_t MB = 1024 * 1024;
  unsigned short* qh    = (unsigned short*)(ws);            // 4 MB
  unsigned short* kh    = (unsigned short*)(ws + 4 * MB);   // 4 MB
  unsigned short* vt    = (unsigned short*)(ws + 8 * MB);   // 4 MB [B,NH,D,S]
  unsigned short* attnb = (unsigned short*)(ws + 12 * MB);  // 4 MB
  unsigned short* Wqb   = (unsigned short*)(ws + 16 * MB);  // 2 MB
  unsigned short* Wkb   = (unsigned short*)(ws + 18 * MB);  // 2 MB
  unsigned short* Wvb   = (unsigned short*)(ws + 20 * MB);  // 2 MB
  unsigned short* Wob   = (unsigned short*)(ws + 22 * MB);  // 2 MB
  unsigned short* qb    = (unsigned short*)(ws + 24 * MB);  // 16 MB
  unsigned short* kb    = (unsigned short*)(ws + 40 * MB);  // 16 MB
  unsigned short* vb    = (unsigned short*)(ws + 56 * MB);  // 16 MB -> 72 MB

  conv_kernel<<<dim3(28672), dim3(256), 0, stream>>>(q, k, v, Wq, Wk, Wv, Wo,
                                                     qb, kb, vb, Wqb, Wkb, Wvb, Wob);
  proj_kernel<<<dim3(768), dim3(256), 0, stream>>>(qb, kb, vb, Wqb, Wkb, Wvb, qh, kh, vt);
  flash_kernel<<<dim3(64, 16), dim3(256), 0, stream>>>(qh, kh, vt, attnb);
  out_kernel<<<dim3(512), dim3(256), 0, stream>>>(attnb, Wob, (float*)d_out);

  (void)in_sizes; (void)n_in; (void)out_size; (void)ws_size;
}